// Round 8
// baseline (827.070 us; speedup 1.0000x reference)
//
#include <hip/hip_runtime.h>
#include <cstdint>
#include <cstddef>

// GraphMambaLayer on MI355X.
// R8: revert BM=128 bounds to (256,2) (R7's (256,3) was neutral/negative);
// LN-gain fold: piw becomes single-A GEMM M=8192 N=4096 (diag(g)W folded at
// transpose time, beta@W folded into bias via bias_fold kernel); u/ubf now
// [8192][2048] (f|b along cols); pow reads with lda=2048 + column offset.
// R7: 778. R6: 788. R5: 754 absmax 0.0625. R4: 832. R3: 928.

typedef unsigned short u16;
typedef __bf16 bf16x8 __attribute__((ext_vector_type(8)));
typedef float f32x4 __attribute__((ext_vector_type(4)));

#define MROWS 8192

__device__ __forceinline__ u16 f2bf(float f){
  unsigned u = __float_as_uint(f);
  u += 0x7FFFu + ((u >> 16) & 1u);           // RNE
  return (u16)(u >> 16);
}
__device__ __forceinline__ float bf2f(u16 v){
  return __uint_as_float((unsigned)v << 16);
}

__device__ __forceinline__ float wred64(float v){
#pragma unroll
  for (int o = 32; o > 0; o >>= 1) v += __shfl_xor(v, o, 64);
  return v;
}

#define GLD16(gp, lp) __builtin_amdgcn_global_load_lds( \
    (const __attribute__((address_space(1))) unsigned int*)(gp), \
    (__attribute__((address_space(3))) unsigned int*)(lp), 16, 0, 0)

// ---------------- merged weight transpose + bf16 convert ---------------------
// dst[n][k] = src[k][oc(n)] * (scl ? scl[k] : 1)   (k >= R -> 0)
struct TDesc { const float* src; u16* dst; const float* scl;
               int R, Kpad, C, zgate, nbx, base; };
struct TPack { TDesc d[16]; };

__global__ __launch_bounds__(256) void transpose_all(TPack p){
  int bid = blockIdx.x;
  TDesc dd = p.d[0];
#pragma unroll
  for (int i = 1; i < 16; ++i) if (bid >= p.d[i].base) dd = p.d[i];
  int lb = bid - dd.base;
  int bx = lb % dd.nbx, by = lb / dd.nbx;

  __shared__ float tile[32][33];
  int n0 = bx << 5, k0 = by << 5;
  int tx = threadIdx.x & 31, ty = threadIdx.x >> 5;
#pragma unroll
  for (int i = 0; i < 32; i += 8){
    int k = k0 + ty + i, n = n0 + tx;
    int oc = n;
    if (dd.zgate){ int g = n >> 5, sl = n & 31;
      oc = (sl < 16) ? (g << 4) + sl : (dd.C >> 1) + (g << 4) + sl - 16; }
    float val = 0.f;
    if (k < dd.R){
      val = dd.src[(size_t)k * dd.C + oc];
      if (dd.scl) val *= dd.scl[k];
    }
    tile[ty + i][tx] = val;
  }
  __syncthreads();
#pragma unroll
  for (int i = 0; i < 32; i += 8){
    int n = n0 + ty + i, k = k0 + tx;
    dd.dst[(size_t)n * dd.Kpad + k] = f2bf(tile[tx][ty + i]);
  }
}

// ---------------- bias fold: out[c][n] = pib[n] + sum_k pnb[k]*W[k][n] -------
// c = d*2+i over (2 dirs x 2 layers), n in [0,2048), W = piw_d layer i.
__global__ __launch_bounds__(256) void bias_fold(
    const float* __restrict__ pib0, const float* __restrict__ pib1,
    const float* __restrict__ pnb0, const float* __restrict__ pnb1,
    const float* __restrict__ piw0, const float* __restrict__ piw1,
    float* __restrict__ outb){
  int c = blockIdx.x >> 3, d = c >> 1, i = c & 1;
  int n = ((blockIdx.x & 7) << 8) + threadIdx.x;
  const float* pib = (d ? pib1 : pib0) + (size_t)i * 2048;
  const float* nb  = (d ? pnb1 : pnb0) + (size_t)i * 512;
  const float* W   = (d ? piw1 : piw0) + (size_t)i * 512 * 2048;
  float a = pib[n];
  for (int k = 0; k < 512; ++k) a += nb[k] * W[(size_t)k * 2048 + n];
  outb[(size_t)c * 2048 + n] = a;
}

// ---------------- attn_maps moments -> sinusoidal encoding -------------------
__global__ __launch_bounds__(256) void stats_enc(
    const float* __restrict__ attn, u16* __restrict__ enc){
  int row = blockIdx.x;
  const float4* a4 = (const float4*)(attn + (size_t)row * 4096);
  int t = threadIdx.x;
  const float inv63 = 1.0f / 63.0f;
  float s0 = 0, sy = 0, sx = 0, sy2 = 0, sx2 = 0;
#pragma unroll
  for (int i = 0; i < 4; ++i){
    int c = t + 256 * i;
    float4 v = a4[c];
    int n = 4 * c;
#pragma unroll
    for (int e = 0; e < 4; ++e){
      float av = (&v.x)[e];
      int nn = n + e;
      float gy = (float)(nn >> 6) * inv63;
      float gx = (float)(nn & 63) * inv63;
      s0 += av; sy += av * gy; sx += av * gx;
      sy2 += av * gy * gy; sx2 += av * gx * gx;
    }
  }
  s0 = wred64(s0); sy = wred64(sy); sx = wred64(sx);
  sy2 = wred64(sy2); sx2 = wred64(sx2);
  __shared__ float red[4][5];
  __shared__ float outv[3];
  int wv = t >> 6, lane = t & 63;
  if (lane == 0){ red[wv][0]=s0; red[wv][1]=sy; red[wv][2]=sx; red[wv][3]=sy2; red[wv][4]=sx2; }
  __syncthreads();
  if (t == 0){
    float S=0, Ay=0, Ax=0, Ay2=0, Ax2=0;
    for (int w = 0; w < 4; ++w){ S+=red[w][0]; Ay+=red[w][1]; Ax+=red[w][2]; Ay2+=red[w][3]; Ax2+=red[w][4]; }
    float denom = S + 1e-8f;
    float cy = Ay / denom, cx = Ax / denom;
    float sp2 = (Ay2 - 2.f*cy*Ay + cy*cy*S + Ax2 - 2.f*cx*Ax + cx*cx*S) / denom;
    outv[0] = cy; outv[1] = cx; outv[2] = sqrtf(fmaxf(sp2, 0.f));
  }
  __syncthreads();
  if (t < 192){
    float cy = outv[0], cx = outv[1];
    float val = 0.f;
    if (t < 128){
      int j = t & 31;
      float fr = expf(-0.28782313662425572f * (float)j);   // ln(10000)/32
      float base = (t < 64) ? cy : cx;
      float ang = base * fr;
      val = ((t >> 5) & 1) ? cosf(ang) : sinf(ang);
    } else if (t == 128) val = outv[2];
    enc[(size_t)row * 192 + t] = f2bf(val);
  }
}

// ---------------- LayerNorm kernels (1 wave / row) ---------------------------
// sc(f32) -> nv = (x-m)*rstd (bf16, NO gain/bias: folded into piw weights)
__global__ __launch_bounds__(256) void ln_norm(
    const float* __restrict__ x, u16* __restrict__ o){
  int row = blockIdx.x * 4 + (threadIdx.x >> 6);
  int lane = threadIdx.x & 63, c = lane * 8;
  const float* xr = x + (size_t)row * 512 + c;
  float v[8];
  *(float4*)(v) = *(const float4*)(xr); *(float4*)(v+4) = *(const float4*)(xr+4);
  float s = 0.f;
#pragma unroll
  for (int j = 0; j < 8; ++j) s += v[j];
  float m = wred64(s) * (1.f/512.f);
  float q = 0.f;
#pragma unroll
  for (int j = 0; j < 8; ++j){ float d = v[j]-m; q += d*d; }
  float rstd = rsqrtf(wred64(q)*(1.f/512.f) + 1e-5f);
  u16 u1[8] __attribute__((aligned(16)));
#pragma unroll
  for (int j = 0; j < 8; ++j) u1[j] = f2bf((v[j]-m)*rstd);
  *(uint4*)(o + (size_t)row*512 + c) = *(const uint4*)u1;
}

// u [8192][2048] (f cols 0-1023, b cols 1024-2047): per-half LN over 1024.
// 16384 virtual rows: row=vr>>1, half=vr&1.
__global__ __launch_bounds__(256) void ln1024(
    const u16* __restrict__ x,
    const float* __restrict__ gf, const float* __restrict__ bfp,
    const float* __restrict__ gb, const float* __restrict__ bbp,
    u16* __restrict__ o){
  int vr = blockIdx.x * 4 + (threadIdx.x >> 6);
  int row = vr >> 1, half = vr & 1;
  int lane = threadIdx.x & 63, c = lane * 16;
  const float* g = half ? gb : gf;
  const float* b = half ? bbp : bfp;
  size_t base = (size_t)row * 2048 + half * 1024 + c;
  u16 raw[16] __attribute__((aligned(16)));
  *(uint4*)(raw)     = *(const uint4*)(x + base);
  *(uint4*)(raw + 8) = *(const uint4*)(x + base + 8);
  float v[16];
#pragma unroll
  for (int j = 0; j < 16; ++j) v[j] = bf2f(raw[j]);
  float s = 0.f;
#pragma unroll
  for (int j = 0; j < 16; ++j) s += v[j];
  float m = wred64(s) * (1.f/1024.f);
  float q = 0.f;
#pragma unroll
  for (int j = 0; j < 16; ++j){ float d = v[j]-m; q += d*d; }
  float rstd = rsqrtf(wred64(q)*(1.f/1024.f) + 1e-5f);
  float G[16], B[16];
#pragma unroll
  for (int i = 0; i < 4; ++i){
    *(float4*)(G + 4*i) = *(const float4*)(g + c + 4*i);
    *(float4*)(B + 4*i) = *(const float4*)(b + c + 4*i);
  }
  u16 u[16] __attribute__((aligned(16)));
#pragma unroll
  for (int j = 0; j < 16; ++j) u[j] = f2bf((v[j]-m)*rstd*G[j] + B[j]);
  *(uint4*)(o + base)     = *(const uint4*)(u);
  *(uint4*)(o + base + 8) = *(const uint4*)(u + 8);
}

// r2(bf16) -> s1 = LN(r2; ng,nb) (bf16), h2 = LN(s1; fg,fb) (bf16)
__global__ __launch_bounds__(256) void ln_double(
    const u16* __restrict__ x,
    const float* __restrict__ ng, const float* __restrict__ nb,
    const float* __restrict__ fg, const float* __restrict__ fbv,
    u16* __restrict__ s1, u16* __restrict__ h2){
  int row = blockIdx.x * 4 + (threadIdx.x >> 6);
  int lane = threadIdx.x & 63, c = lane * 8;
  const u16* xr = x + (size_t)row * 512 + c;
  u16 raw[8] __attribute__((aligned(16)));
  *(uint4*)(raw) = *(const uint4*)(xr);
  float v[8];
#pragma unroll
  for (int j = 0; j < 8; ++j) v[j] = bf2f(raw[j]);
  float s = 0.f;
#pragma unroll
  for (int j = 0; j < 8; ++j) s += v[j];
  float m = wred64(s) * (1.f/512.f);
  float q = 0.f;
#pragma unroll
  for (int j = 0; j < 8; ++j){ float d = v[j]-m; q += d*d; }
  float rstd = rsqrtf(wred64(q)*(1.f/512.f) + 1e-5f);
  float NG[8],NB[8],FG[8],FB[8];
  *(float4*)(NG)=*(const float4*)(ng+c); *(float4*)(NG+4)=*(const float4*)(ng+c+4);
  *(float4*)(NB)=*(const float4*)(nb+c); *(float4*)(NB+4)=*(const float4*)(nb+c+4);
  *(float4*)(FG)=*(const float4*)(fg+c); *(float4*)(FG+4)=*(const float4*)(fg+c+4);
  *(float4*)(FB)=*(const float4*)(fbv+c);*(float4*)(FB+4)=*(const float4*)(fbv+c+4);
  float w[8];
#pragma unroll
  for (int j = 0; j < 8; ++j) w[j] = (v[j]-m)*rstd*NG[j] + NB[j];
  u16 us[8] __attribute__((aligned(16)));
#pragma unroll
  for (int j = 0; j < 8; ++j) us[j] = f2bf(w[j]);
  *(uint4*)(s1 + (size_t)row*512 + c) = *(const uint4*)us;
  float s2 = 0.f;
#pragma unroll
  for (int j = 0; j < 8; ++j) s2 += w[j];
  float m2 = wred64(s2) * (1.f/512.f);
  float q2 = 0.f;
#pragma unroll
  for (int j = 0; j < 8; ++j){ float d = w[j]-m2; q2 += d*d; }
  float rstd2 = rsqrtf(wred64(q2)*(1.f/512.f) + 1e-5f);
  u16 u[8] __attribute__((aligned(16)));
#pragma unroll
  for (int j = 0; j < 8; ++j) u[j] = f2bf((w[j]-m2)*rstd2*FG[j] + FB[j]);
  *(uint4*)(h2 + (size_t)row*512 + c) = *(const uint4*)u;
}

// ---------------- bf16 MFMA GEMM, A[M,.lda] x BT[N,K]^T, fused epilogues -----
// Row-stacked A: blocks with m0>=8192 use A1/BT1/bias1 (A row index mod 8192).
// EPI 0: bf16 out = gelu(v+bias)                    (ldo = N)
// EPI 1: f32 out = v+bias+res_f32                   (ldo = N)
// EPI 2: f32 out = (v+bias+res_bf16)*km[row]        (ldo = N)
// EPI 3: bf16 u[row][d*1024 + zidx] = silu(z)*sigmoid(g); d = col>>11,
//        weight rows z/gate-interleaved per direction; bias0/bias1 by d,
//        original per-direction layout (z: [0,1024), gate: +1024)
// EPI 4: bf16 out[(row&8191)*ldo + (row>>13)*512 + col] = v+bias+res_f32
template<int EPI, int BM>
__global__ __launch_bounds__(256, (BM == 64) ? 4 : 2) void gemm_bt(
    const u16* __restrict__ A0, const u16* __restrict__ A1, int lda,
    const u16* __restrict__ BT0, const u16* __restrict__ BT1,
    const float* __restrict__ bias0, const float* __restrict__ bias1,
    const void* __restrict__ res,
    float* __restrict__ outF, u16* __restrict__ outB,
    const float* __restrict__ km,
    int K, int N, int ldo){
  constexpr int MR = BM / 32;
  __shared__ u16 Asm[BM * 64];
  __shared__ u16 Bsm[128 * 64];
  const int tid = threadIdx.x, wv = tid >> 6, lane = tid & 63;
  const int m0 = blockIdx.y * BM, n0 = blockIdx.x << 7;
  const int wr = wv >> 1, wc = wv & 1;
  const u16* A = (m0 < MROWS) ? A0 : A1;
  const u16* BT = (m0 < MROWS) ? BT0 : BT1;
  const float* bias = (m0 < MROWS) ? bias0 : bias1;
  const int mbase = m0 & (MROWS - 1);

  const int rowin = lane >> 3;
  const int ksrc = ((16 * (lane & 7)) ^ (rowin << 4)) >> 1;
  const int rA = wv * (BM / 4) + rowin;
  const int rB = (wv << 5) + rowin;
  const u16* gA = A + (size_t)(mbase + rA) * lda + ksrc;
  const u16* gB = BT + (size_t)(n0 + rB) * K + ksrc;
  u16* ldsA = Asm + wv * (BM / 4) * 64;
  u16* ldsB = Bsm + (wv << 11);

  f32x4 acc[MR][4] = {};
  const int cbase = 16 * (lane >> 4);
  const int swz = (lane & 7) << 4;

  for (int kt = 0; kt < K; kt += 64){
#pragma unroll
    for (int it = 0; it < BM / 32; ++it)
      GLD16(gA + (size_t)it * 8 * lda + kt, ldsA + it * 512);
#pragma unroll
    for (int it = 0; it < 4; ++it)
      GLD16(gB + (size_t)it * 8 * K + kt, ldsB + it * 512);
    __syncthreads();
#pragma unroll
    for (int ks = 0; ks < 64; ks += 32){
      const int cs = ((2 * ks + cbase) ^ swz) >> 1;
      bf16x8 af[MR], bfr[4];
#pragma unroll
      for (int m = 0; m < MR; ++m)
        af[m] = *reinterpret_cast<const bf16x8*>(&Asm[(wr*(BM/2) + m*16 + (lane & 15)) * 64 + cs]);
#pragma unroll
      for (int n = 0; n < 4; ++n)
        bfr[n] = *reinterpret_cast<const bf16x8*>(&Bsm[(wc*64 + n*16 + (lane & 15)) * 64 + cs]);
#pragma unroll
      for (int m = 0; m < MR; ++m)
#pragma unroll
        for (int n = 0; n < 4; ++n)
          acc[m][n] = __builtin_amdgcn_mfma_f32_16x16x32_bf16(af[m], bfr[n], acc[m][n], 0, 0, 0);
    }
    __syncthreads();
  }

  const int lr = (lane >> 4) << 2, lc = lane & 15;
#pragma unroll
  for (int m = 0; m < MR; ++m){
    const int grow0 = m0 + wr * (BM/2) + m * 16 + lr;
    if constexpr (EPI == 3){
#pragma unroll
      for (int n = 0; n < 4; n += 2){
        const int zc = n0 + wc * 64 + n * 16 + lc;     // global col [0,4096)
        const int dsel = zc >> 11;                      // direction
        const int loc = zc & 2047;
        const int bi = ((loc >> 5) << 4) + lc;          // per-dir z index
        const float* bz_p = dsel ? bias1 : bias0;
        const float bz = bz_p[bi], bg = bz_p[1024 + bi];
        const int ucol = (dsel << 10) + bi;
#pragma unroll
        for (int r = 0; r < 4; ++r){
          float z = acc[m][n][r] + bz;
          float g = acc[m][n + 1][r] + bg;
          outB[(size_t)(grow0 + r) * ldo + ucol] =
              f2bf((z / (1.f + expf(-z))) * (1.f / (1.f + expf(-g))));
        }
      }
    } else {
#pragma unroll
      for (int n = 0; n < 4; ++n){
        const int col = n0 + wc * 64 + n * 16 + lc;
        const float bv = bias[col];
#pragma unroll
        for (int r = 0; r < 4; ++r){
          const int grow = grow0 + r;
          float v = acc[m][n][r] + bv;
          if constexpr (EPI == 0){
            outB[(size_t)grow * ldo + col] = f2bf(0.5f * v * (1.f + erff(v * 0.70710678118654752f)));
          } else if constexpr (EPI == 1){
            outF[(size_t)grow * ldo + col] = v + ((const float*)res)[(size_t)grow * N + col];
          } else if constexpr (EPI == 2){
            outF[(size_t)grow * ldo + col] =
                (v + bf2f(((const u16*)res)[(size_t)grow * N + col])) * km[grow];
          } else {  // EPI 4
            const int rowout = grow & (MROWS - 1);
            const int coloff = (grow >> 13) << 9;
            outB[(size_t)rowout * ldo + coloff + col] =
                f2bf(v + ((const float*)res)[(size_t)rowout * N + col]);
          }
        }
      }
    }
  }
}

// -----------------------------------------------------------------------------
extern "C" void kernel_launch(void* const* d_in, const int* in_sizes, int n_in,
                              void* d_out, int out_size, void* d_ws, size_t ws_size,
                              hipStream_t stream){
  (void)in_sizes; (void)n_in; (void)out_size; (void)ws_size;
  const float* s_in   = (const float*)d_in[0];
  const float* attn   = (const float*)d_in[1];
  const float* km     = (const float*)d_in[2];
  const float* se_w1  = (const float*)d_in[3];
  const float* se_b1  = (const float*)d_in[4];
  const float* se_w2  = (const float*)d_in[5];
  const float* se_b2  = (const float*)d_in[6];
  const float* png[2] = {(const float*)d_in[7],  (const float*)d_in[15]};
  const float* pnb[2] = {(const float*)d_in[8],  (const float*)d_in[16]};
  const float* ppiw[2]= {(const float*)d_in[9],  (const float*)d_in[17]};
  const float* ppib[2]= {(const float*)d_in[10], (const float*)d_in[18]};
  const float* ppow[2]= {(const float*)d_in[11], (const float*)d_in[19]};
  const float* ppob[2]= {(const float*)d_in[12], (const float*)d_in[20]};
  const float* pig[2] = {(const float*)d_in[13], (const float*)d_in[21]};
  const float* pibt[2]= {(const float*)d_in[14], (const float*)d_in[22]};
  const float* mrg_w  = (const float*)d_in[23];
  const float* mrg_b  = (const float*)d_in[24];
  const float* nrm_g  = (const float*)d_in[25];
  const float* nrm_b  = (const float*)d_in[26];
  const float* ffn_ng = (const float*)d_in[27];
  const float* ffn_nb = (const float*)d_in[28];
  const float* ffn_w1 = (const float*)d_in[29];
  const float* ffn_b1 = (const float*)d_in[30];
  const float* ffn_w2 = (const float*)d_in[31];
  const float* ffn_b2 = (const float*)d_in[32];
  float* out = (float*)d_out;

  char* ws = (char*)d_ws;
  size_t off = 0;
  auto alloc = [&](size_t bytes)->char*{
    char* p = ws + off; off += (bytes + 255) & ~(size_t)255; return p; };

  u16* w_sew1 = (u16*)alloc(512 * 192 * 2);
  u16* w_sew2 = (u16*)alloc(512 * 512 * 2);
  u16* w_piwC[2]; u16* w_pow[2][2];
  for (int i = 0; i < 2; ++i) w_piwC[i] = (u16*)alloc((size_t)4096 * 512 * 2);
  for (int d = 0; d < 2; ++d)
    for (int i = 0; i < 2; ++i)
      w_pow[d][i] = (u16*)alloc(512 * 1024 * 2);
  u16* w_mrg[2]; u16* w_ffn1[2]; u16* w_ffn2[2];
  for (int i = 0; i < 2; ++i){
    w_mrg[i]  = (u16*)alloc(512 * 1024 * 2);
    w_ffn1[i] = (u16*)alloc(2048 * 512 * 2);
    w_ffn2[i] = (u16*)alloc(512 * 2048 * 2);
  }
  float* pibC = (float*)alloc((size_t)4 * 2048 * 4);   // folded piw bias
  u16*   enc  = (u16*)alloc((size_t)MROWS * 192 * 2);
  u16*   t1h2 = (u16*)alloc((size_t)MROWS * 512 * 2);
  float* sc   = (float*)alloc((size_t)MROWS * 512 * 4);
  u16*   hnv  = (u16*)alloc((size_t)MROWS * 512 * 2);   // normalized (no g/b)
  char*  big  = alloc((size_t)MROWS * 2048 * 2);        // u / r2 / t2
  u16*   u    = (u16*)big;                              // [8192][2048]
  u16*   r2   = (u16*)big;
  u16*   t2   = (u16*)big;
  u16*   ubf  = (u16*)alloc((size_t)MROWS * 2048 * 2);  // [8192][2048]
  u16*   fbuf = (u16*)alloc((size_t)MROWS * 1024 * 2);
  u16*   s1   = (u16*)alloc((size_t)MROWS * 512 * 2);

  // ---- weight conversion: ONE kernel over 16 descriptors ----
  TPack pk; int base = 0, di = 0;
  auto push = [&](const float* src, u16* dst, int R, int Kpad, int C, int zg,
                  const float* scl){
    TDesc& t = pk.d[di++];
    t.src = src; t.dst = dst; t.scl = scl;
    t.R = R; t.Kpad = Kpad; t.C = C; t.zgate = zg;
    t.nbx = C / 32; t.base = base;
    base += (C / 32) * (Kpad / 32);
  };
  push(se_w1, w_sew1, 129, 192, 512, 0, nullptr);
  push(se_w2, w_sew2, 512, 512, 512, 0, nullptr);
  for (int i = 0; i < 2; ++i)
    for (int d = 0; d < 2; ++d){
      // piw: rows d*2048.. of combined BT, LN gain folded via row-scale
      push(ppiw[d] + (size_t)i*512*2048, w_piwC[i] + (size_t)d*2048*512,
           512, 512, 2048, 1, png[d] + i*512);
      push(ppow[d] + (size_t)i*1024*512, w_pow[d][i], 1024, 1024, 512, 0, nullptr);
    }
  for (int i = 0; i < 2; ++i){
    push(mrg_w  + (size_t)i*1024*512, w_mrg[i],  1024, 1024, 512, 0, nullptr);
    push(ffn_w1 + (size_t)i*512*2048, w_ffn1[i], 512, 512, 2048, 0, nullptr);
    push(ffn_w2 + (size_t)i*2048*512, w_ffn2[i], 2048, 2048, 512, 0, nullptr);
  }
  transpose_all<<<base, 256, 0, stream>>>(pk);
  bias_fold<<<32, 256, 0, stream>>>(ppib[0], ppib[1], pnb[0], pnb[1],
                                    ppiw[0], ppiw[1], pibC);

  // ---- spatial encoding ----
  stats_enc<<<MROWS, 256, 0, stream>>>(attn, enc);
  gemm_bt<0,64><<<dim3(4, 128), 256, 0, stream>>>(enc, enc, 192,
      w_sew1, w_sew1, se_b1, se_b1, nullptr, nullptr, t1h2, nullptr, 192, 512, 512);
  gemm_bt<1,64><<<dim3(4, 128), 256, 0, stream>>>(t1h2, t1h2, 512,
      w_sew2, w_sew2, se_b2, se_b2, s_in, sc, nullptr, nullptr, 512, 512, 512);

  // ---- layers (order/rv/flip cancel: all per-token) ----
  for (int i = 0; i < 2; ++i){
    ln_norm<<<MROWS/4, 256, 0, stream>>>(sc, hnv);
    // single-A piw: [8192,512] @ [512,4096] -> u [8192][2048] (zgate fused)
    gemm_bt<3,128><<<dim3(32, 64), 256, 0, stream>>>(hnv, hnv, 512,
        w_piwC[i], w_piwC[i], pibC + (size_t)i*2048, pibC + (size_t)(2+i)*2048,
        nullptr, nullptr, u, nullptr, 512, 4096, 2048);
    ln1024<<<(2*MROWS)/4, 256, 0, stream>>>(u,
        pig[0]+i*1024, pibt[0]+i*1024, pig[1]+i*1024, pibt[1]+i*1024, ubf);
    // stacked f/b: ubf cols (d*1024..) @ pow_d + sc -> fbuf (f 0-511 | b 512-1023)
    gemm_bt<4,64><<<dim3(4, 256), 256, 0, stream>>>(ubf, ubf + 1024, 2048,
        w_pow[0][i], w_pow[1][i], ppob[0]+i*512, ppob[1]+i*512,
        sc, nullptr, fbuf, nullptr, 1024, 512, 1024);
    gemm_bt<4,64><<<dim3(4, 128), 256, 0, stream>>>(fbuf, fbuf, 1024,
        w_mrg[i], w_mrg[i], mrg_b+i*512, mrg_b+i*512,
        sc, nullptr, r2, nullptr, 1024, 512, 512);
    ln_double<<<MROWS/4, 256, 0, stream>>>(r2, nrm_g+i*512, nrm_b+i*512,
        ffn_ng+i*512, ffn_nb+i*512, s1, t1h2);
    gemm_bt<0,128><<<dim3(16, 64), 256, 0, stream>>>(t1h2, t1h2, 512,
        w_ffn1[i], w_ffn1[i], ffn_b1+i*2048, ffn_b1+i*2048,
        nullptr, nullptr, t2, nullptr, 512, 2048, 2048);
    gemm_bt<2,64><<<dim3(4, 128), 256, 0, stream>>>(t2, t2, 2048,
        w_ffn2[i], w_ffn2[i], ffn_b2+i*512, ffn_b2+i*512,
        s1, (i == 1 ? out : sc), nullptr, km, 2048, 512, 512);
  }
}

// Round 9
// 749.858 us; speedup vs baseline: 1.1030x; 1.1030x over previous
//
#include <hip/hip_runtime.h>
#include <cstdint>
#include <cstddef>

// GraphMambaLayer on MI355X.
// R9 = R5 exact revert (best measured: 754 us, absmax 0.0625).
// Ledger: R6 8-phase@K=512 +34us (prologue/epilogue exposed at nt2=4, 1blk/CU);
// R7 launch_bounds(256,3) +24us; R8 LN-fold +73us (serial bias_fold dispatch,
// B=4MB==L2 working-set bump, 4KB-stride A rows). All reverted.
// Structure: f/b direction stacking (piw/pow/ln1024 M=16384 single dispatches),
// BM=64 GEMMs at 4 blocks/CU, BM=128 at 2; bf16 r2/s1 streams; order/flip
// cancellation (ssm is per-token) eliminates argsort entirely.

typedef unsigned short u16;
typedef __bf16 bf16x8 __attribute__((ext_vector_type(8)));
typedef float f32x4 __attribute__((ext_vector_type(4)));

#define MROWS 8192

__device__ __forceinline__ u16 f2bf(float f){
  unsigned u = __float_as_uint(f);
  u += 0x7FFFu + ((u >> 16) & 1u);           // RNE
  return (u16)(u >> 16);
}
__device__ __forceinline__ float bf2f(u16 v){
  return __uint_as_float((unsigned)v << 16);
}

__device__ __forceinline__ float wred64(float v){
#pragma unroll
  for (int o = 32; o > 0; o >>= 1) v += __shfl_xor(v, o, 64);
  return v;
}

#define GLD16(gp, lp) __builtin_amdgcn_global_load_lds( \
    (const __attribute__((address_space(1))) unsigned int*)(gp), \
    (__attribute__((address_space(3))) unsigned int*)(lp), 16, 0, 0)

// ---------------- merged weight transpose + bf16 convert ---------------------
struct TDesc { const float* src; u16* dst; int R, Kpad, C, zgate, nbx, base; };
struct TPack { TDesc d[16]; };

__global__ __launch_bounds__(256) void transpose_all(TPack p){
  int bid = blockIdx.x;
  TDesc dd = p.d[0];
#pragma unroll
  for (int i = 1; i < 16; ++i) if (bid >= p.d[i].base) dd = p.d[i];
  int lb = bid - dd.base;
  int bx = lb % dd.nbx, by = lb / dd.nbx;

  __shared__ float tile[32][33];
  int n0 = bx << 5, k0 = by << 5;
  int tx = threadIdx.x & 31, ty = threadIdx.x >> 5;
#pragma unroll
  for (int i = 0; i < 32; i += 8){
    int k = k0 + ty + i, n = n0 + tx;
    int oc = n;
    if (dd.zgate){ int g = n >> 5, sl = n & 31;
      oc = (sl < 16) ? (g << 4) + sl : (dd.C >> 1) + (g << 4) + sl - 16; }
    tile[ty + i][tx] = (k < dd.R) ? dd.src[(size_t)k * dd.C + oc] : 0.f;
  }
  __syncthreads();
#pragma unroll
  for (int i = 0; i < 32; i += 8){
    int n = n0 + ty + i, k = k0 + tx;
    dd.dst[(size_t)n * dd.Kpad + k] = f2bf(tile[tx][ty + i]);
  }
}

// ---------------- attn_maps moments -> sinusoidal encoding -------------------
__global__ __launch_bounds__(256) void stats_enc(
    const float* __restrict__ attn, u16* __restrict__ enc){
  int row = blockIdx.x;
  const float4* a4 = (const float4*)(attn + (size_t)row * 4096);
  int t = threadIdx.x;
  const float inv63 = 1.0f / 63.0f;
  float s0 = 0, sy = 0, sx = 0, sy2 = 0, sx2 = 0;
#pragma unroll
  for (int i = 0; i < 4; ++i){
    int c = t + 256 * i;
    float4 v = a4[c];
    int n = 4 * c;
#pragma unroll
    for (int e = 0; e < 4; ++e){
      float av = (&v.x)[e];
      int nn = n + e;
      float gy = (float)(nn >> 6) * inv63;
      float gx = (float)(nn & 63) * inv63;
      s0 += av; sy += av * gy; sx += av * gx;
      sy2 += av * gy * gy; sx2 += av * gx * gx;
    }
  }
  s0 = wred64(s0); sy = wred64(sy); sx = wred64(sx);
  sy2 = wred64(sy2); sx2 = wred64(sx2);
  __shared__ float red[4][5];
  __shared__ float outv[3];
  int wv = t >> 6, lane = t & 63;
  if (lane == 0){ red[wv][0]=s0; red[wv][1]=sy; red[wv][2]=sx; red[wv][3]=sy2; red[wv][4]=sx2; }
  __syncthreads();
  if (t == 0){
    float S=0, Ay=0, Ax=0, Ay2=0, Ax2=0;
    for (int w = 0; w < 4; ++w){ S+=red[w][0]; Ay+=red[w][1]; Ax+=red[w][2]; Ay2+=red[w][3]; Ax2+=red[w][4]; }
    float denom = S + 1e-8f;
    float cy = Ay / denom, cx = Ax / denom;
    float sp2 = (Ay2 - 2.f*cy*Ay + cy*cy*S + Ax2 - 2.f*cx*Ax + cx*cx*S) / denom;
    outv[0] = cy; outv[1] = cx; outv[2] = sqrtf(fmaxf(sp2, 0.f));
  }
  __syncthreads();
  if (t < 192){
    float cy = outv[0], cx = outv[1];
    float val = 0.f;
    if (t < 128){
      int j = t & 31;
      float fr = expf(-0.28782313662425572f * (float)j);   // ln(10000)/32
      float base = (t < 64) ? cy : cx;
      float ang = base * fr;
      val = ((t >> 5) & 1) ? cosf(ang) : sinf(ang);
    } else if (t == 128) val = outv[2];
    enc[(size_t)row * 192 + t] = f2bf(val);
  }
}

// ---------------- LayerNorm kernels (1 wave / row) ---------------------------
// sc(f32) -> hf=LN(g1,b1), hb=LN(g2,b2) both bf16 (adjacent planes of hcat)
__global__ __launch_bounds__(256) void ln_dual(
    const float* __restrict__ x,
    const float* __restrict__ g1, const float* __restrict__ b1,
    const float* __restrict__ g2, const float* __restrict__ b2,
    u16* __restrict__ o1, u16* __restrict__ o2){
  int row = blockIdx.x * 4 + (threadIdx.x >> 6);
  int lane = threadIdx.x & 63, c = lane * 8;
  const float* xr = x + (size_t)row * 512 + c;
  float v[8];
  *(float4*)(v) = *(const float4*)(xr); *(float4*)(v+4) = *(const float4*)(xr+4);
  float s = 0.f;
#pragma unroll
  for (int j = 0; j < 8; ++j) s += v[j];
  float m = wred64(s) * (1.f/512.f);
  float q = 0.f;
#pragma unroll
  for (int j = 0; j < 8; ++j){ float d = v[j]-m; q += d*d; }
  float rstd = rsqrtf(wred64(q)*(1.f/512.f) + 1e-5f);
  float G1[8],B1[8],G2[8],B2[8];
  *(float4*)(G1)=*(const float4*)(g1+c); *(float4*)(G1+4)=*(const float4*)(g1+c+4);
  *(float4*)(B1)=*(const float4*)(b1+c); *(float4*)(B1+4)=*(const float4*)(b1+c+4);
  *(float4*)(G2)=*(const float4*)(g2+c); *(float4*)(G2+4)=*(const float4*)(g2+c+4);
  *(float4*)(B2)=*(const float4*)(b2+c); *(float4*)(B2+4)=*(const float4*)(b2+c+4);
  u16 u1[8] __attribute__((aligned(16)));
  u16 u2[8] __attribute__((aligned(16)));
#pragma unroll
  for (int j = 0; j < 8; ++j){
    float nv = (v[j]-m)*rstd;
    u1[j] = f2bf(nv*G1[j]+B1[j]);
    u2[j] = f2bf(nv*G2[j]+B2[j]);
  }
  *(uint4*)(o1 + (size_t)row*512 + c) = *(const uint4*)u1;
  *(uint4*)(o2 + (size_t)row*512 + c) = *(const uint4*)u2;
}

// bf16 in -> bf16 out LN over 1024; 16384 stacked rows, params per row-half
__global__ __launch_bounds__(256) void ln1024(
    const u16* __restrict__ x,
    const float* __restrict__ gf, const float* __restrict__ bfp,
    const float* __restrict__ gb, const float* __restrict__ bbp,
    u16* __restrict__ o){
  int row = blockIdx.x * 4 + (threadIdx.x >> 6);
  int lane = threadIdx.x & 63, c = lane * 16;
  const float* g = (row >> 13) ? gb : gf;
  const float* b = (row >> 13) ? bbp : bfp;
  const u16* xr = x + (size_t)row * 1024 + c;
  u16 raw[16] __attribute__((aligned(16)));
  *(uint4*)(raw)     = *(const uint4*)(xr);
  *(uint4*)(raw + 8) = *(const uint4*)(xr + 8);
  float v[16];
#pragma unroll
  for (int j = 0; j < 16; ++j) v[j] = bf2f(raw[j]);
  float s = 0.f;
#pragma unroll
  for (int j = 0; j < 16; ++j) s += v[j];
  float m = wred64(s) * (1.f/1024.f);
  float q = 0.f;
#pragma unroll
  for (int j = 0; j < 16; ++j){ float d = v[j]-m; q += d*d; }
  float rstd = rsqrtf(wred64(q)*(1.f/1024.f) + 1e-5f);
  float G[16], B[16];
#pragma unroll
  for (int i = 0; i < 4; ++i){
    *(float4*)(G + 4*i) = *(const float4*)(g + c + 4*i);
    *(float4*)(B + 4*i) = *(const float4*)(b + c + 4*i);
  }
  u16 u[16] __attribute__((aligned(16)));
#pragma unroll
  for (int j = 0; j < 16; ++j) u[j] = f2bf((v[j]-m)*rstd*G[j] + B[j]);
  *(uint4*)(o + (size_t)row*1024 + c)     = *(const uint4*)(u);
  *(uint4*)(o + (size_t)row*1024 + c + 8) = *(const uint4*)(u + 8);
}

// r2(bf16) -> s1 = LN(r2; ng,nb) (bf16), h2 = LN(s1; fg,fb) (bf16)
__global__ __launch_bounds__(256) void ln_double(
    const u16* __restrict__ x,
    const float* __restrict__ ng, const float* __restrict__ nb,
    const float* __restrict__ fg, const float* __restrict__ fbv,
    u16* __restrict__ s1, u16* __restrict__ h2){
  int row = blockIdx.x * 4 + (threadIdx.x >> 6);
  int lane = threadIdx.x & 63, c = lane * 8;
  const u16* xr = x + (size_t)row * 512 + c;
  u16 raw[8] __attribute__((aligned(16)));
  *(uint4*)(raw) = *(const uint4*)(xr);
  float v[8];
#pragma unroll
  for (int j = 0; j < 8; ++j) v[j] = bf2f(raw[j]);
  float s = 0.f;
#pragma unroll
  for (int j = 0; j < 8; ++j) s += v[j];
  float m = wred64(s) * (1.f/512.f);
  float q = 0.f;
#pragma unroll
  for (int j = 0; j < 8; ++j){ float d = v[j]-m; q += d*d; }
  float rstd = rsqrtf(wred64(q)*(1.f/512.f) + 1e-5f);
  float NG[8],NB[8],FG[8],FB[8];
  *(float4*)(NG)=*(const float4*)(ng+c); *(float4*)(NG+4)=*(const float4*)(ng+c+4);
  *(float4*)(NB)=*(const float4*)(nb+c); *(float4*)(NB+4)=*(const float4*)(nb+c+4);
  *(float4*)(FG)=*(const float4*)(fg+c); *(float4*)(FG+4)=*(const float4*)(fg+c+4);
  *(float4*)(FB)=*(const float4*)(fbv+c);*(float4*)(FB+4)=*(const float4*)(fbv+c+4);
  float w[8];
#pragma unroll
  for (int j = 0; j < 8; ++j) w[j] = (v[j]-m)*rstd*NG[j] + NB[j];
  u16 us[8] __attribute__((aligned(16)));
#pragma unroll
  for (int j = 0; j < 8; ++j) us[j] = f2bf(w[j]);
  *(uint4*)(s1 + (size_t)row*512 + c) = *(const uint4*)us;
  float s2 = 0.f;
#pragma unroll
  for (int j = 0; j < 8; ++j) s2 += w[j];
  float m2 = wred64(s2) * (1.f/512.f);
  float q2 = 0.f;
#pragma unroll
  for (int j = 0; j < 8; ++j){ float d = w[j]-m2; q2 += d*d; }
  float rstd2 = rsqrtf(wred64(q2)*(1.f/512.f) + 1e-5f);
  u16 u[8] __attribute__((aligned(16)));
#pragma unroll
  for (int j = 0; j < 8; ++j) u[j] = f2bf((w[j]-m2)*rstd2*FG[j] + FB[j]);
  *(uint4*)(h2 + (size_t)row*512 + c) = *(const uint4*)u;
}

// ---------------- bf16 MFMA GEMM, A[M,K] x BT[N,K]^T, fused epilogues --------
// Stacked-direction support: blocks with m0>=8192 use BT1/bias1.
// EPI 0: bf16 out = gelu(v+bias)                    (ldo = N)
// EPI 1: f32 out = v+bias+res_f32                   (ldo = N)
// EPI 2: f32 out = (v+bias+res_bf16)*km[row]        (ldo = N)
// EPI 3: bf16 out[N/2] = silu(z)*sigmoid(g); weight rows z/gate-interleaved in
//        16-wide groups; bias in ORIGINAL layout (z: [0,N/2), gate: +N/2)
// EPI 4: bf16 out[(row&8191)*ldo + (row>>13)*512 + col] = v+bias+res_f32
template<int EPI, int BM>
__global__ __launch_bounds__(256, (BM == 64) ? 4 : 2) void gemm_bt(
    const u16* __restrict__ A,
    const u16* __restrict__ BT0, const u16* __restrict__ BT1,
    const float* __restrict__ bias0, const float* __restrict__ bias1,
    const void* __restrict__ res,
    float* __restrict__ outF, u16* __restrict__ outB,
    const float* __restrict__ km,
    int K, int N, int ldo){
  constexpr int MR = BM / 32;
  __shared__ u16 Asm[BM * 64];
  __shared__ u16 Bsm[128 * 64];
  const int tid = threadIdx.x, wv = tid >> 6, lane = tid & 63;
  const int m0 = blockIdx.y * BM, n0 = blockIdx.x << 7;
  const int wr = wv >> 1, wc = wv & 1;
  const u16* BT = (m0 < MROWS) ? BT0 : BT1;
  const float* bias = (m0 < MROWS) ? bias0 : bias1;

  const int rowin = lane >> 3;
  const int ksrc = ((16 * (lane & 7)) ^ (rowin << 4)) >> 1;
  const int rA = wv * (BM / 4) + rowin;
  const int rB = (wv << 5) + rowin;
  const u16* gA = A + (size_t)(m0 + rA) * K + ksrc;
  const u16* gB = BT + (size_t)(n0 + rB) * K + ksrc;
  u16* ldsA = Asm + wv * (BM / 4) * 64;
  u16* ldsB = Bsm + (wv << 11);

  f32x4 acc[MR][4] = {};
  const int cbase = 16 * (lane >> 4);
  const int swz = (lane & 7) << 4;

  for (int kt = 0; kt < K; kt += 64){
#pragma unroll
    for (int it = 0; it < BM / 32; ++it)
      GLD16(gA + (size_t)it * 8 * K + kt, ldsA + it * 512);
#pragma unroll
    for (int it = 0; it < 4; ++it)
      GLD16(gB + (size_t)it * 8 * K + kt, ldsB + it * 512);
    __syncthreads();
#pragma unroll
    for (int ks = 0; ks < 64; ks += 32){
      const int cs = ((2 * ks + cbase) ^ swz) >> 1;
      bf16x8 af[MR], bfr[4];
#pragma unroll
      for (int m = 0; m < MR; ++m)
        af[m] = *reinterpret_cast<const bf16x8*>(&Asm[(wr*(BM/2) + m*16 + (lane & 15)) * 64 + cs]);
#pragma unroll
      for (int n = 0; n < 4; ++n)
        bfr[n] = *reinterpret_cast<const bf16x8*>(&Bsm[(wc*64 + n*16 + (lane & 15)) * 64 + cs]);
#pragma unroll
      for (int m = 0; m < MR; ++m)
#pragma unroll
        for (int n = 0; n < 4; ++n)
          acc[m][n] = __builtin_amdgcn_mfma_f32_16x16x32_bf16(af[m], bfr[n], acc[m][n], 0, 0, 0);
    }
    __syncthreads();
  }

  const int lr = (lane >> 4) << 2, lc = lane & 15;
#pragma unroll
  for (int m = 0; m < MR; ++m){
    const int grow0 = m0 + wr * (BM/2) + m * 16 + lr;
    if constexpr (EPI == 3){
#pragma unroll
      for (int n = 0; n < 4; n += 2){
        const int zc = n0 + wc * 64 + n * 16 + lc;
        const int bi = ((zc >> 5) << 4) + lc;          // original z-col
        const float bz = bias[bi], bg = bias[(N >> 1) + bi];
        const int ucol = ((n0 + wc * 64) >> 1) + (n << 3) + lc;
#pragma unroll
        for (int r = 0; r < 4; ++r){
          float z = acc[m][n][r] + bz;
          float g = acc[m][n + 1][r] + bg;
          outB[(size_t)(grow0 + r) * ldo + ucol] =
              f2bf((z / (1.f + expf(-z))) * (1.f / (1.f + expf(-g))));
        }
      }
    } else {
#pragma unroll
      for (int n = 0; n < 4; ++n){
        const int col = n0 + wc * 64 + n * 16 + lc;
        const float bv = bias[col];
#pragma unroll
        for (int r = 0; r < 4; ++r){
          const int grow = grow0 + r;
          float v = acc[m][n][r] + bv;
          if constexpr (EPI == 0){
            outB[(size_t)grow * ldo + col] = f2bf(0.5f * v * (1.f + erff(v * 0.70710678118654752f)));
          } else if constexpr (EPI == 1){
            outF[(size_t)grow * ldo + col] = v + ((const float*)res)[(size_t)grow * N + col];
          } else if constexpr (EPI == 2){
            outF[(size_t)grow * ldo + col] =
                (v + bf2f(((const u16*)res)[(size_t)grow * N + col])) * km[grow];
          } else {  // EPI 4
            const int rowout = grow & (MROWS - 1);
            const int coloff = (grow >> 13) << 9;
            outB[(size_t)rowout * ldo + coloff + col] =
                f2bf(v + ((const float*)res)[(size_t)rowout * N + col]);
          }
        }
      }
    }
  }
}

// -----------------------------------------------------------------------------
extern "C" void kernel_launch(void* const* d_in, const int* in_sizes, int n_in,
                              void* d_out, int out_size, void* d_ws, size_t ws_size,
                              hipStream_t stream){
  (void)in_sizes; (void)n_in; (void)out_size; (void)ws_size;
  const float* s_in   = (const float*)d_in[0];
  const float* attn   = (const float*)d_in[1];
  const float* km     = (const float*)d_in[2];
  const float* se_w1  = (const float*)d_in[3];
  const float* se_b1  = (const float*)d_in[4];
  const float* se_w2  = (const float*)d_in[5];
  const float* se_b2  = (const float*)d_in[6];
  const float* png[2] = {(const float*)d_in[7],  (const float*)d_in[15]};
  const float* pnb[2] = {(const float*)d_in[8],  (const float*)d_in[16]};
  const float* ppiw[2]= {(const float*)d_in[9],  (const float*)d_in[17]};
  const float* ppib[2]= {(const float*)d_in[10], (const float*)d_in[18]};
  const float* ppow[2]= {(const float*)d_in[11], (const float*)d_in[19]};
  const float* ppob[2]= {(const float*)d_in[12], (const float*)d_in[20]};
  const float* pig[2] = {(const float*)d_in[13], (const float*)d_in[21]};
  const float* pibt[2]= {(const float*)d_in[14], (const float*)d_in[22]};
  const float* mrg_w  = (const float*)d_in[23];
  const float* mrg_b  = (const float*)d_in[24];
  const float* nrm_g  = (const float*)d_in[25];
  const float* nrm_b  = (const float*)d_in[26];
  const float* ffn_ng = (const float*)d_in[27];
  const float* ffn_nb = (const float*)d_in[28];
  const float* ffn_w1 = (const float*)d_in[29];
  const float* ffn_b1 = (const float*)d_in[30];
  const float* ffn_w2 = (const float*)d_in[31];
  const float* ffn_b2 = (const float*)d_in[32];
  float* out = (float*)d_out;

  char* ws = (char*)d_ws;
  size_t off = 0;
  auto alloc = [&](size_t bytes)->char*{
    char* p = ws + off; off += (bytes + 255) & ~(size_t)255; return p; };

  u16* w_sew1 = (u16*)alloc(512 * 192 * 2);
  u16* w_sew2 = (u16*)alloc(512 * 512 * 2);
  u16* w_piw[2][2]; u16* w_pow[2][2];
  for (int d = 0; d < 2; ++d)
    for (int i = 0; i < 2; ++i){
      w_piw[d][i] = (u16*)alloc(2048 * 512 * 2);
      w_pow[d][i] = (u16*)alloc(512 * 1024 * 2);
    }
  u16* w_mrg[2]; u16* w_ffn1[2]; u16* w_ffn2[2];
  for (int i = 0; i < 2; ++i){
    w_mrg[i]  = (u16*)alloc(512 * 1024 * 2);
    w_ffn1[i] = (u16*)alloc(2048 * 512 * 2);
    w_ffn2[i] = (u16*)alloc(512 * 2048 * 2);
  }
  u16*   enc  = (u16*)alloc((size_t)MROWS * 192 * 2);
  u16*   t1h2 = (u16*)alloc((size_t)MROWS * 512 * 2);
  float* sc   = (float*)alloc((size_t)MROWS * 512 * 4);
  u16*   hcat = (u16*)alloc((size_t)2 * MROWS * 512 * 2);
  char*  big  = alloc((size_t)MROWS * 2048 * 2);
  u16*   upre = (u16*)big;
  u16*   r2   = (u16*)big;
  u16*   t2   = (u16*)big;
  u16*   ubf  = (u16*)alloc((size_t)2 * MROWS * 1024 * 2);
  u16*   fbuf = (u16*)alloc((size_t)MROWS * 1024 * 2);
  u16*   s1   = (u16*)alloc((size_t)MROWS * 512 * 2);

  // ---- weight conversion: ONE kernel over 16 descriptors ----
  TPack pk; int base = 0, di = 0;
  auto push = [&](const float* src, u16* dst, int R, int Kpad, int C, int zg){
    TDesc& t = pk.d[di++];
    t.src = src; t.dst = dst; t.R = R; t.Kpad = Kpad; t.C = C; t.zgate = zg;
    t.nbx = C / 32; t.base = base;
    base += (C / 32) * (Kpad / 32);
  };
  push(se_w1, w_sew1, 129, 192, 512, 0);
  push(se_w2, w_sew2, 512, 512, 512, 0);
  for (int d = 0; d < 2; ++d)
    for (int i = 0; i < 2; ++i){
      push(ppiw[d] + (size_t)i*512*2048, w_piw[d][i], 512, 512, 2048, 1);
      push(ppow[d] + (size_t)i*1024*512, w_pow[d][i], 1024, 1024, 512, 0);
    }
  for (int i = 0; i < 2; ++i){
    push(mrg_w  + (size_t)i*1024*512, w_mrg[i],  1024, 1024, 512, 0);
    push(ffn_w1 + (size_t)i*512*2048, w_ffn1[i], 512, 512, 2048, 0);
    push(ffn_w2 + (size_t)i*2048*512, w_ffn2[i], 2048, 2048, 512, 0);
  }
  transpose_all<<<base, 256, 0, stream>>>(pk);

  // ---- spatial encoding ----
  stats_enc<<<MROWS, 256, 0, stream>>>(attn, enc);
  gemm_bt<0,64><<<dim3(4, 128), 256, 0, stream>>>(enc, w_sew1, w_sew1, se_b1, se_b1,
      nullptr, nullptr, t1h2, nullptr, 192, 512, 512);
  gemm_bt<1,64><<<dim3(4, 128), 256, 0, stream>>>(t1h2, w_sew2, w_sew2, se_b2, se_b2,
      s_in, sc, nullptr, nullptr, 512, 512, 512);

  // ---- layers (order/rv/flip cancel: all per-token) ----
  for (int i = 0; i < 2; ++i){
    ln_dual<<<MROWS/4, 256, 0, stream>>>(sc, png[0]+i*512, pnb[0]+i*512,
        png[1]+i*512, pnb[1]+i*512, hcat, hcat + (size_t)MROWS*512);
    // stacked f/b zi + silu*sigmoid: [16384,512]@[512,2048] -> u [16384][1024]
    gemm_bt<3,128><<<dim3(16, 128), 256, 0, stream>>>(hcat,
        w_piw[0][i], w_piw[1][i], ppib[0]+(size_t)i*2048, ppib[1]+(size_t)i*2048,
        nullptr, nullptr, upre, nullptr, 512, 2048, 1024);
    ln1024<<<(2*MROWS)/4, 256, 0, stream>>>(upre,
        pig[0]+i*1024, pibt[0]+i*1024, pig[1]+i*1024, pibt[1]+i*1024, ubf);
    gemm_bt<4,64><<<dim3(4, 256), 256, 0, stream>>>(ubf,
        w_pow[0][i], w_pow[1][i], ppob[0]+i*512, ppob[1]+i*512,
        sc, nullptr, fbuf, nullptr, 1024, 512, 1024);
    gemm_bt<4,64><<<dim3(4, 128), 256, 0, stream>>>(fbuf,
        w_mrg[i], w_mrg[i], mrg_b+i*512, mrg_b+i*512,
        sc, nullptr, r2, nullptr, 1024, 512, 512);
    ln_double<<<MROWS/4, 256, 0, stream>>>(r2, nrm_g+i*512, nrm_b+i*512,
        ffn_ng+i*512, ffn_nb+i*512, s1, t1h2);
    gemm_bt<0,128><<<dim3(16, 64), 256, 0, stream>>>(t1h2,
        w_ffn1[i], w_ffn1[i], ffn_b1+i*2048, ffn_b1+i*2048,
        nullptr, nullptr, t2, nullptr, 512, 2048, 2048);
    gemm_bt<2,64><<<dim3(4, 128), 256, 0, stream>>>(t2,
        w_ffn2[i], w_ffn2[i], ffn_b2+i*512, ffn_b2+i*512,
        s1, (i == 1 ? out : sc), nullptr, km, 2048, 512, 512);
  }
}